// Round 7
// baseline (77.816 us; speedup 1.0000x reference)
//
#include <hip/hip_runtime.h>
#include <math.h>

#define IW 256
#define IH 256
#define NG 1000
#define CHUNK 256
#define TILE_W 16
#define TILE_H 16
#define TILES_X (IW / TILE_W)   // 16
#define TILES_Y (IH / TILE_H)   // 16
#define ALPHA_MAX 0.999f
#define LOG2_EPS -19.93157f     // log2(1e-6) cull threshold
#define LN2 0.6931471805599453f
#define INV_LN2 1.4426950408889634f

// Single fused kernel. Block = 16x16 pixel tile, 1 px/thread.
// Gaussians processed in index order in 4 chunks of 256:
//   A) per-thread param compute + tile-AABB cull (registers only)
//   B) ballot + cross-wave prefix compact survivors into LDS (order kept)
//   C) ordered scan-composite of survivors; (T, accum) persist in registers.
__global__ __launch_bounds__(256) void splat2d_kernel(
    const float* __restrict__ means,
    const float* __restrict__ quats,
    const float* __restrict__ scales,
    const float* __restrict__ rgbs,
    const float* __restrict__ opacities,
    float* __restrict__ out)
{
    __shared__ float4 s0[CHUNK];   // cx, cy, A, B
    __shared__ float4 s1[CHUNK];   // C, lop, col, 0
    __shared__ int wave_cnt[4];

    const int tid = threadIdx.x;
    const int tx0 = blockIdx.x * TILE_W;
    const int ty0 = blockIdx.y * TILE_H;

    const float midx = (float)tx0 + 0.5f * (TILE_W - 1) + 0.5f;
    const float midy = (float)ty0 + 0.5f * (TILE_H - 1) + 0.5f;
    const float hx = 0.5f * (TILE_W - 1);
    const float hy = 0.5f * (TILE_H - 1);

    const float px = (float)(tx0 + (tid & (TILE_W - 1))) + 0.5f;
    const float py = (float)(ty0 + (tid >> 4)) + 0.5f;

    const int lane = tid & 63;
    const int w    = tid >> 6;

    float T = 1.0f;
    float accum = 0.0f;

    for (int c0 = 0; c0 < NG; c0 += CHUNK) {
        // --- A: param compute + cull (no LDS touched) ---
        bool keep = false;
        float cx, cy, A, B, Cc, lop, col;
        const int n = c0 + tid;
        if (n < NG) {
            float2 mu = ((const float2*)means)[n];
            float2 sc = ((const float2*)scales)[n];
            float q   = quats[n];
            float opa = opacities[n];
            float rgb = rgbs[n];

            float sq, cq;
            __sincosf(q, &sq, &cq);
            float sx2 = sc.x * sc.x, sy2 = sc.y * sc.y;
            float a11 = cq * cq * sx2 + sq * sq * sy2;
            float a12 = cq * sq * (sx2 - sy2);
            float a22 = sq * sq * sx2 + cq * cq * sy2;
            float det = a11 * a22 - a12 * a12;
            float inv = INV_LN2 / det;
            A   = -0.5f * a22 * inv;
            B   =          a12 * inv;
            Cc  = -0.5f * a11 * inv;
            float op = 1.0f / (1.0f + __expf(-opa));
            lop = __log2f(op);
            col = 1.0f / (1.0f + __expf(-rgb));
            cx = mu.x; cy = mu.y;

            float t  = fmaxf((lop - LOG2_EPS) * LN2, 0.0f);
            float rx = sqrtf(2.0f * a11 * t);
            float ry = sqrtf(2.0f * a22 * t);

            keep = (fabsf(cx - midx) <= hx + rx) &&
                   (fabsf(cy - midy) <= hy + ry);
        }

        // --- B: compact into LDS (order-preserving) ---
        __syncthreads();   // previous chunk's scan is done reading s0/s1/wave_cnt
        unsigned long long m = __ballot(keep);
        int rank = __popcll(m & ((1ull << lane) - 1ull));
        if (lane == 0) wave_cnt[w] = __popcll(m);
        __syncthreads();
        int c0w = wave_cnt[0], c1w = wave_cnt[1], c2w = wave_cnt[2], c3w = wave_cnt[3];
        int off = (w > 0 ? c0w : 0) + (w > 1 ? c1w : 0) + (w > 2 ? c2w : 0);
        const int cnt = c0w + c1w + c2w + c3w;
        if (keep) {
            s0[off + rank] = make_float4(cx, cy, A, B);
            s1[off + rank] = make_float4(Cc, lop, col, 0.0f);
        }
        __syncthreads();

        // --- C: ordered scan-composite ---
        for (int k = 0; k < cnt; ++k) {
            float4 q0 = s0[k];
            float4 q1 = s1[k];
            float dx = px - q0.x;
            float dy = py - q0.y;
            float t  = fmaf(q0.w, dy, q0.z * dx);               // A*dx + B*dy
            float e  = fmaf(t, dx, fmaf(q1.x * dy, dy, q1.y));  // + C*dy^2 + lop
            float alpha = fminf(__builtin_amdgcn_exp2f(e), ALPHA_MAX);
            accum = fmaf(alpha * T, q1.z, accum);
            T = fmaf(-alpha, T, T);
            if (((k & 7) == 7) && __all(T < 1e-5f)) break;
        }
    }

    const int pix = (ty0 + (tid >> 4)) * IW + tx0 + (tid & (TILE_W - 1));
    out[pix] = accum;
}

extern "C" void kernel_launch(void* const* d_in, const int* in_sizes, int n_in,
                              void* d_out, int out_size, void* d_ws, size_t ws_size,
                              hipStream_t stream) {
    const float* means     = (const float*)d_in[0];
    const float* quats     = (const float*)d_in[1];
    const float* scales    = (const float*)d_in[2];
    const float* rgbs      = (const float*)d_in[3];
    const float* opacities = (const float*)d_in[4];
    float* out = (float*)d_out;

    splat2d_kernel<<<dim3(TILES_X, TILES_Y), 256, 0, stream>>>(
        means, quats, scales, rgbs, opacities, out);
}

// Round 8
// 67.271 us; speedup vs baseline: 1.1568x; 1.1568x over previous
//
#include <hip/hip_runtime.h>
#include <math.h>

#define IW 256
#define IH 256
#define NG 1000
#define NSEG 4
#define SEG (NG / NSEG)         // 250 gaussians per wave-segment
#define TILE_W 16
#define TILE_H 4
#define TILES_X (IW / TILE_W)   // 16
#define TILES_Y (IH / TILE_H)   // 64
#define ALPHA_MAX 0.999f
#define LOG2_EPS -19.93157f     // log2(1e-6) cull threshold
#define LN2 0.6931471805599453f
#define INV_LN2 1.4426950408889634f

// Single fused kernel, fully parallel inside the block.
// Block = 16x4 pixel tile, 4 waves; wave w owns ordered gaussian segment
// [w*250, (w+1)*250):
//   A) 4 rounds of 64: per-lane param compute + tile-AABB cull,
//      per-wave ballot compact into the wave's PRIVATE LDS region
//      (order preserved; no cross-wave sync needed).
//   B) wave scans its survivors for the tile's 64 pixels (1 px/lane),
//      producing per-segment partials (c_w, T_w).
//   C) one __syncthreads(); wave 0 folds the 4 partials per pixel in
//      segment order and stores.
__global__ __launch_bounds__(256) void splat2d_kernel(
    const float* __restrict__ means,
    const float* __restrict__ quats,
    const float* __restrict__ scales,
    const float* __restrict__ rgbs,
    const float* __restrict__ opacities,
    float* __restrict__ out)
{
    __shared__ float4 s0[NSEG][SEG];   // cx, cy, A, B      (16 KB)
    __shared__ float4 s1[NSEG][SEG];   // C, lop, col, 0    (16 KB)
    __shared__ float2 comb[64][NSEG];  // (c, T) partials   (2 KB)

    const int tid  = threadIdx.x;
    const int lane = tid & 63;
    const int w    = tid >> 6;
    const int tx0  = blockIdx.x * TILE_W;
    const int ty0  = blockIdx.y * TILE_H;

    const float midx = (float)tx0 + 0.5f * (TILE_W - 1) + 0.5f;
    const float midy = (float)ty0 + 0.5f * (TILE_H - 1) + 0.5f;
    const float hx = 0.5f * (TILE_W - 1);
    const float hy = 0.5f * (TILE_H - 1);

    // --- A: per-wave cull + compact into private LDS region ---
    int cnt = 0;
    const int base = w * SEG;
    #pragma unroll
    for (int r = 0; r < 4; ++r) {
        const int o = r * 64 + lane;         // offset within segment
        bool keep = false;
        float cx, cy, A, B, Cc, lop, col;
        if (o < SEG) {
            const int n = base + o;
            float2 mu = ((const float2*)means)[n];
            float2 sc = ((const float2*)scales)[n];
            float q   = quats[n];
            float opa = opacities[n];
            float rgb = rgbs[n];

            float sq, cq;
            __sincosf(q, &sq, &cq);
            float sx2 = sc.x * sc.x, sy2 = sc.y * sc.y;
            float a11 = cq * cq * sx2 + sq * sq * sy2;
            float a12 = cq * sq * (sx2 - sy2);
            float a22 = sq * sq * sx2 + cq * cq * sy2;
            float det = a11 * a22 - a12 * a12;
            float inv = INV_LN2 / det;
            A   = -0.5f * a22 * inv;
            B   =          a12 * inv;
            Cc  = -0.5f * a11 * inv;
            float op = 1.0f / (1.0f + __expf(-opa));
            lop = __log2f(op);
            col = 1.0f / (1.0f + __expf(-rgb));
            cx = mu.x; cy = mu.y;

            float t  = fmaxf((lop - LOG2_EPS) * LN2, 0.0f);
            float rx = sqrtf(2.0f * a11 * t);
            float ry = sqrtf(2.0f * a22 * t);

            keep = (fabsf(cx - midx) <= hx + rx) &&
                   (fabsf(cy - midy) <= hy + ry);
        }
        unsigned long long m = __ballot(keep);
        int rank = __popcll(m & ((1ull << lane) - 1ull));
        if (keep) {
            s0[w][cnt + rank] = make_float4(cx, cy, A, B);
            s1[w][cnt + rank] = make_float4(Cc, lop, col, 0.0f);
        }
        cnt += __popcll(m);
    }

    // --- B: per-wave ordered scan over its survivors ---
    const float px = (float)(tx0 + (lane & (TILE_W - 1))) + 0.5f;
    const float py = (float)(ty0 + (lane >> 4)) + 0.5f;

    float T = 1.0f;
    float accum = 0.0f;
    for (int k = 0; k < cnt; ++k) {
        float4 q0 = s0[w][k];
        float4 q1 = s1[w][k];
        float dx = px - q0.x;
        float dy = py - q0.y;
        float t  = fmaf(q0.w, dy, q0.z * dx);               // A*dx + B*dy
        float e  = fmaf(t, dx, fmaf(q1.x * dy, dy, q1.y));  // + C*dy^2 + lop
        float alpha = fminf(__builtin_amdgcn_exp2f(e), ALPHA_MAX);
        accum = fmaf(alpha * T, q1.z, accum);
        T = fmaf(-alpha, T, T);
    }
    comb[lane][w] = make_float2(accum, T);

    // --- C: fold segments in order, store ---
    __syncthreads();
    if (w == 0) {
        float c = 0.0f, Tt = 1.0f;
        #pragma unroll
        for (int s = 0; s < NSEG; ++s) {
            float2 v = comb[lane][s];
            c  = fmaf(Tt, v.x, c);
            Tt *= v.y;
        }
        out[(ty0 + (lane >> 4)) * IW + tx0 + (lane & (TILE_W - 1))] = c;
    }
}

extern "C" void kernel_launch(void* const* d_in, const int* in_sizes, int n_in,
                              void* d_out, int out_size, void* d_ws, size_t ws_size,
                              hipStream_t stream) {
    const float* means     = (const float*)d_in[0];
    const float* quats     = (const float*)d_in[1];
    const float* scales    = (const float*)d_in[2];
    const float* rgbs      = (const float*)d_in[3];
    const float* opacities = (const float*)d_in[4];
    float* out = (float*)d_out;

    splat2d_kernel<<<dim3(TILES_X, TILES_Y), 256, 0, stream>>>(
        means, quats, scales, rgbs, opacities, out);
}